// Round 11
// baseline (2569.044 us; speedup 1.0000x reference)
//
#include <hip/hip_runtime.h>
#include <stdint.h>

typedef __attribute__((ext_vector_type(8))) short bf16x8;
typedef __attribute__((ext_vector_type(4))) float f32x4;

#define NE 320000
#define NNODES 20000
// LDS: H 32768 | W0 16384 | W1 16384 | bias 3584 | colsum 512 = 69632 (2 blocks/CU)
#define SMEM_BYTES 69632

__device__ __forceinline__ unsigned short f2bf(float f) {
  union { float f; unsigned int u; } v; v.f = f;
  unsigned int u = v.u;
  u += 0x7fffu + ((u >> 16) & 1u);  // RNE
  return (unsigned short)(u >> 16);
}

__device__ __forceinline__ void gload_lds16(const void* g, void* l) {
  __builtin_amdgcn_global_load_lds((const __attribute__((address_space(1))) void*)g,
                                   (__attribute__((address_space(3))) void*)l, 16, 0, 0);
}

// ---- weight packing: W[K][N] fp32 -> A-fragment order (W^T frags) ----
// frag idx = s*NG + g (s = kstep of 32, g = 16-wide out group); 1KB per frag.
// element j of lane ln = W[s*32 + (ln>>4)*8 + j][g*16 + (ln&15)]
struct PackArgs {
  const float* src[8];
  unsigned short* dst[8];
  int K[8];
  int N[8];
};

__global__ void pack_weights(PackArgs a) {
  int m = blockIdx.y;
  int K = a.K[m], N = a.N[m];
  int NG = N >> 4;
  int total = (K >> 5) * NG * 64;
  int idx = blockIdx.x * 256 + threadIdx.x;
  if (idx >= total) return;
  int ln = idx & 63, f = idx >> 6;
  int g = f % NG, s = f / NG;
  const float* src = a.src[m];
  int krow = s * 32 + ((ln >> 4) & 3) * 8;
  int col = g * 16 + (ln & 15);
  bf16x8 p;
#pragma unroll
  for (int j = 0; j < 8; ++j) p[j] = (short)f2bf(src[(size_t)(krow + j) * N + col]);
  *(bf16x8*)(a.dst[m] + (size_t)idx * 8) = p;
}

// RNE bf16x8 from 8 fp32 (R1-proven numerics)
__device__ __forceinline__ bf16x8 cvt8(const f32x4& a, const f32x4& b) {
  bf16x8 r;
#pragma unroll
  for (int j = 0; j < 4; ++j) {
    r[j] = (short)f2bf(a[j]);
    r[4 + j] = (short)f2bf(b[j]);
  }
  return r;
}

// write relu(accT + bias) into H[m][n] bf16 (64 rows x 256 cols), stride 512B,
// XOR-swizzled; zero acc
__device__ __forceinline__ void store_H(char* Hb, const float* biasL, int boff,
                                        f32x4 (&acc)[2][4], int wm, int wn, int t, int cl) {
#pragma unroll
  for (int mg = 0; mg < 2; ++mg) {
    int m = wm * 32 + mg * 16 + cl;
    int sw = (m & 7) << 4;
    int mb = m * 512;
#pragma unroll
    for (int g = 0; g < 4; ++g) {
      int n = wn * 64 + g * 16 + t * 4;
      f32x4 bv = *(const f32x4*)(biasL + boff + n);
      f32x4 v = acc[mg][g] + bv;
#pragma unroll
      for (int j = 0; j < 4; ++j) v[j] = fmaxf(v[j], 0.0f);
      unsigned lo = (unsigned)f2bf(v[0]) | ((unsigned)f2bf(v[1]) << 16);
      unsigned hi = (unsigned)f2bf(v[2]) | ((unsigned)f2bf(v[3]) << 16);
      *(unsigned*)(Hb + ((mb + n * 2) ^ sw)) = lo;
      *(unsigned*)(Hb + ((mb + n * 2 + 4) ^ sw)) = hi;
      f32x4 z = {0.f, 0.f, 0.f, 0.f};
      acc[mg][g] = z;
    }
  }
}

// MODE 0: edge MLP (K1=512, X = [g|n_s|n_r|edges], agg atomics, e_sum)
// MODE 1: node MLP (K1=384, X = [g|nodes|agg], n_sum)
// pwAll = contiguous packed weights (w1|w2|w3|w4), 16KB chunks (kstep-of-32 each).
// Sync: __syncthreads() only. Overlap: {sync; issue stageW(c+1); compute(c)}.
// stageW LDS destinations are WAVE-UNIFORM (base + slice*1024), per-lane only on
// the GLOBAL source — the m104/m108 rule; per-lane LDS dest (R6-R10's tid*16) is
// the suspected cause of the 1.4GB scratch-write / 2.8% MfmaUtil pathology.
template <int MODE>
__global__ __launch_bounds__(512, 4) void fused_mlp(
    const float* __restrict__ gvec, const float* __restrict__ nodes,
    const float* __restrict__ third, const int* __restrict__ senders,
    const int* __restrict__ receivers, const unsigned short* __restrict__ pwAll,
    const float* __restrict__ b1, const float* __restrict__ b2,
    const float* __restrict__ b3, const float* __restrict__ b4,
    float* __restrict__ outp, float* __restrict__ aggp, float* __restrict__ colsum) {
  constexpr int K1 = (MODE == 0) ? 512 : 384;
  constexpr int C1 = K1 / 32;          // L1 chunks of K=32 (16 / 12) — even
  constexpr int CT = C1 + 8 + 8 + 4;   // + L2 (8) + L3 (8) + L4 (4, K=64xN=128)
  constexpr int NROWS = (MODE == 0) ? NE : NNODES;

  extern __shared__ char smem[];
  char* Hb = smem;                        // 32768 : H [64][256] bf16 / [64][128] f32
  char* Wb0 = smem + 32768;               // 16384
  char* Wb1 = smem + 49152;               // 16384
  float* biasL = (float*)(smem + 65536);  // 896 floats
  float* csL = (float*)(smem + 69120);    // 128 floats

  const int tid = threadIdx.x;
  const int lane = tid & 63;
  const int wv = tid >> 6;            // 0..7
  const int wn = wv & 3;              // n-group quad (cols wn*64..+63)
  const int wm = wv >> 2;             // row half (rows wm*32..+31)
  const int t = lane >> 4, cl = lane & 15;
  const int row0 = blockIdx.x * 64;

  // ---- prologue: bias + colsum LDS ----
  for (int i = tid; i < 896; i += 512) {
    float bvv;
    if (i < 256) bvv = b1[i];
    else if (i < 512) bvv = b2[i - 256];
    else if (i < 768) bvv = b3[i - 512];
    else bvv = b4[i - 768];
    biasL[i] = bvv;
  }
  if (tid < 128) csL[tid] = 0.0f;

  // per-lane source row indices (2 m-groups of 16 rows)
  int ri[2], r1[2], r2[2];
#pragma unroll
  for (int mg = 0; mg < 2; ++mg) {
    int i = row0 + wm * 32 + mg * 16 + cl;
    if (MODE == 0) {
      ri[mg] = i;
      r1[mg] = senders[i];
      r2[mg] = receivers[i];
    } else {
      int iv = i < NROWS ? i : (NROWS - 1);
      ri[mg] = iv;
      r1[mg] = iv;
      r2[mg] = iv;
    }
  }

  // wave-uniform LDS staging: wave wv stages 1KB slices {2wv, 2wv+1} of the 16KB chunk
  auto stageW = [&](int gc) {
    if (gc >= CT) return;
    const char* p = (const char*)pwAll + (size_t)gc * 16384;
    char* d = (gc & 1) ? Wb1 : Wb0;
    const int s0 = wv << 1;  // wave-uniform slice index
    gload_lds16(p + (s0 << 10) + lane * 16, d + (s0 << 10));
    gload_lds16(p + ((s0 + 1) << 10) + lane * 16, d + ((s0 + 1) << 10));
  };

  // named ping/pong X buffers — all indices compile-time (rule #20 hedge)
  f32x4 xfA[2][2], xfB[2][2];
#define LOAD_X(BUF, c)                                                              \
  {                                                                                 \
    _Pragma("unroll") for (int mg = 0; mg < 2; ++mg) {                              \
      const int k0 = (c) * 32;                                                      \
      const int reg = k0 >> 7;                                                      \
      const int off = (k0 & 127) + t * 8;                                           \
      const float* sp;                                                              \
      if (MODE == 0) {                                                              \
        sp = (reg == 0)   ? gvec + off                                              \
             : (reg == 1) ? nodes + (size_t)r1[mg] * 128 + off                      \
             : (reg == 2) ? nodes + (size_t)r2[mg] * 128 + off                      \
                          : third + (size_t)ri[mg] * 128 + off;                     \
      } else {                                                                      \
        sp = (reg == 0)   ? gvec + off                                              \
             : (reg == 1) ? nodes + (size_t)r1[mg] * 128 + off                      \
                          : third + (size_t)r2[mg] * 128 + off;                     \
      }                                                                             \
      BUF[mg][0] = *(const f32x4*)sp;                                               \
      BUF[mg][1] = *(const f32x4*)(sp + 4);                                         \
    }                                                                               \
  }

  // one L1 step: sync; prefetch W(c+1); prefetch X(c+1)->XFN; MFMA on XFC + W(c)
#define L1_STEP(XFC, XFN, c)                                                        \
  {                                                                                 \
    __syncthreads();                                                                \
    stageW((c) + 1);                                                                \
    if ((c) + 1 < C1) LOAD_X(XFN, (c) + 1);                                         \
    bf16x8 xb[2];                                                                   \
    _Pragma("unroll") for (int mg = 0; mg < 2; ++mg)                                \
        xb[mg] = cvt8(XFC[mg][0], XFC[mg][1]);                                      \
    const char* wb = ((c) & 1) ? Wb1 : Wb0;                                         \
    _Pragma("unroll") for (int g = 0; g < 4; ++g) {                                 \
      bf16x8 af = *(const bf16x8*)(wb + ((wn * 4 + g) << 10) + lane * 16);          \
      _Pragma("unroll") for (int mg = 0; mg < 2; ++mg)                              \
          acc[mg][g] =                                                              \
              __builtin_amdgcn_mfma_f32_16x16x32_bf16(af, xb[mg], acc[mg][g], 0, 0, 0); \
    }                                                                               \
  }

  f32x4 acc[2][4];
  {
    f32x4 z = {0.f, 0.f, 0.f, 0.f};
#pragma unroll
    for (int mg = 0; mg < 2; ++mg)
#pragma unroll
      for (int g = 0; g < 4; ++g) acc[mg][g] = z;
  }

  stageW(0);
  LOAD_X(xfA, 0);

  // ---------------- layer 1 (explicit ping/pong pairs; C1 is even) ----------------
#pragma unroll
  for (int cc = 0; cc < C1 / 2; ++cc) {
    L1_STEP(xfA, xfB, 2 * cc);
    L1_STEP(xfB, xfA, 2 * cc + 1);
  }
  // store_H writes Hb; no wave reads Hb during L1 -> no extra sync needed here
  store_H(Hb, biasL, 0, acc, wm, wn, t, cl);

  // ---------------- layers 2,3 ----------------
#pragma unroll
  for (int L = 0; L < 2; ++L) {
    const int base = C1 + L * 8;
#pragma unroll
    for (int c = 0; c < 8; ++c) {
      __syncthreads();               // store_H visible (c=0); W(base+c) drained
      stageW(base + c + 1);
      const char* wb = ((base + c) & 1) ? Wb1 : Wb0;
      bf16x8 bfm[2];
#pragma unroll
      for (int mg = 0; mg < 2; ++mg) {
        int m = wm * 32 + mg * 16 + cl;
        int off = (m * 512 + c * 64 + t * 16) ^ ((m & 7) << 4);
        bfm[mg] = *(const bf16x8*)(Hb + off);
      }
#pragma unroll
      for (int g = 0; g < 4; ++g) {
        bf16x8 af = *(const bf16x8*)(wb + ((wn * 4 + g) << 10) + lane * 16);
#pragma unroll
        for (int mg = 0; mg < 2; ++mg)
          acc[mg][g] = __builtin_amdgcn_mfma_f32_16x16x32_bf16(af, bfm[mg], acc[mg][g], 0, 0, 0);
      }
    }
    __syncthreads();                 // all Hb reads of this layer retired
    store_H(Hb, biasL, 256 + L * 256, acc, wm, wn, t, cl);
  }

  // ---------------- layer 4 (N=128, chunks = K=64 x 128) ----------------
  {
    const int base = C1 + 16;
#pragma unroll
    for (int c = 0; c < 4; ++c) {
      __syncthreads();
      stageW(base + c + 1);          // guarded >= CT inside
      const char* wb = ((base + c) & 1) ? Wb1 : Wb0;
#pragma unroll
      for (int s2 = 0; s2 < 2; ++s2) {
        bf16x8 bfm[2];
#pragma unroll
        for (int mg = 0; mg < 2; ++mg) {
          int m = wm * 32 + mg * 16 + cl;
          int off = (m * 512 + c * 128 + s2 * 64 + t * 16) ^ ((m & 7) << 4);
          bfm[mg] = *(const bf16x8*)(Hb + off);
        }
#pragma unroll
        for (int g = 0; g < 2; ++g) {
          bf16x8 af = *(const bf16x8*)(wb + ((s2 * 8 + wn * 2 + g) << 10) + lane * 16);
#pragma unroll
          for (int mg = 0; mg < 2; ++mg)
            acc[mg][g] = __builtin_amdgcn_mfma_f32_16x16x32_bf16(af, bfm[mg], acc[mg][g], 0, 0, 0);
        }
      }
    }
  }
  __syncthreads();                   // all Hb (H3) reads retired before overwrite

  // ---------------- epilogue ----------------
  // write acc + b4 as f32 into Hb [64][128], stride 512B, swizzled
#pragma unroll
  for (int mg = 0; mg < 2; ++mg) {
    int m = wm * 32 + mg * 16 + cl;
    int sw = (m & 7) << 4;
    int mb = m * 512;
#pragma unroll
    for (int g = 0; g < 2; ++g) {
      int n = wn * 32 + g * 16 + t * 4;
      f32x4 bv = *(const f32x4*)(biasL + 768 + n);
      f32x4 v = acc[mg][g] + bv;
      float2 p0 = {v[0], v[1]}, p1 = {v[2], v[3]};
      *(float2*)(Hb + ((mb + n * 4) ^ sw)) = p0;
      *(float2*)(Hb + ((mb + n * 4 + 8) ^ sw)) = p1;
    }
  }
  __syncthreads();

  {
    int r = tid >> 3, cw = tid & 7;  // 64 rows x 8 col-groups
    int e = row0 + r;
    bool valid = (MODE == 0) ? true : (e < NROWS);
    f32x4 o[4];
#pragma unroll
    for (int i = 0; i < 4; ++i)
      o[i] = *(const f32x4*)(Hb + ((r * 512 + cw * 64 + i * 16) ^ ((r & 7) << 4)));
    if (valid) {
      float* op = outp + (size_t)e * 128 + cw * 16;
#pragma unroll
      for (int i = 0; i < 4; ++i) *(f32x4*)(op + i * 4) = o[i];
      if (MODE == 0) {
        float* ap = aggp + (size_t)receivers[e] * 128 + cw * 16;
#pragma unroll
        for (int i = 0; i < 4; ++i)
#pragma unroll
          for (int j = 0; j < 4; ++j) atomicAdd(ap + i * 4 + j, o[i][j]);
      }
    }
    // column sums: reduce 8 rows within wave, then LDS, then global
#pragma unroll
    for (int i = 0; i < 4; ++i)
#pragma unroll
      for (int j = 0; j < 4; ++j) {
        float v = valid ? o[i][j] : 0.0f;
        v += __shfl_xor(v, 8);
        v += __shfl_xor(v, 16);
        v += __shfl_xor(v, 32);
        if (lane < 8) atomicAdd(&csL[cw * 16 + i * 4 + j], v);
      }
  }
  __syncthreads();
  if (tid < 128) atomicAdd(colsum + tid, csL[tid]);
#undef LOAD_X
#undef L1_STEP
}

// tiny fp32 global MLP: x = [g | n_sum | e_sum]
__global__ void global_mlp(const float* __restrict__ g, const float* __restrict__ nsum,
                           const float* __restrict__ esum, const float* __restrict__ w1,
                           const float* __restrict__ bb1, const float* __restrict__ w2,
                           const float* __restrict__ bb2, const float* __restrict__ w3,
                           const float* __restrict__ bb3, const float* __restrict__ w4,
                           const float* __restrict__ bb4, float* __restrict__ outg) {
  __shared__ float x[384], h1[256], h2[256], h3[256];
  int tq = threadIdx.x;
  if (tq < 128) x[tq] = g[tq];
  else if (tq < 256) x[tq] = nsum[tq - 128];
  else x[tq] = esum[tq - 256];
  __syncthreads();
  if (tq < 256) {
    float a = bb1[tq];
    for (int k = 0; k < 384; ++k) a = fmaf(x[k], w1[k * 256 + tq], a);
    h1[tq] = fmaxf(a, 0.f);
  }
  __syncthreads();
  if (tq < 256) {
    float a = bb2[tq];
    for (int k = 0; k < 256; ++k) a = fmaf(h1[k], w2[k * 256 + tq], a);
    h2[tq] = fmaxf(a, 0.f);
  }
  __syncthreads();
  if (tq < 256) {
    float a = bb3[tq];
    for (int k = 0; k < 256; ++k) a = fmaf(h2[k], w3[k * 256 + tq], a);
    h3[tq] = fmaxf(a, 0.f);
  }
  __syncthreads();
  if (tq < 128) {
    float a = bb4[tq];
    for (int k = 0; k < 256; ++k) a = fmaf(h3[k], w4[k * 128 + tq], a);
    outg[tq] = a;
  }
}

extern "C" void kernel_launch(void* const* d_in, const int* in_sizes, int n_in, void* d_out,
                              int out_size, void* d_ws, size_t ws_size, hipStream_t stream) {
  const float* g = (const float*)d_in[0];
  const float* nodes = (const float*)d_in[1];
  const float* edges = (const float*)d_in[2];
  const int* senders = (const int*)d_in[3];
  const int* receivers = (const int*)d_in[4];
  const float* ew[4] = {(const float*)d_in[5], (const float*)d_in[7], (const float*)d_in[9],
                        (const float*)d_in[11]};
  const float* eb[4] = {(const float*)d_in[6], (const float*)d_in[8], (const float*)d_in[10],
                        (const float*)d_in[12]};
  const float* nw[4] = {(const float*)d_in[13], (const float*)d_in[15], (const float*)d_in[17],
                        (const float*)d_in[19]};
  const float* nb[4] = {(const float*)d_in[14], (const float*)d_in[16], (const float*)d_in[18],
                        (const float*)d_in[20]};
  const float* gw[4] = {(const float*)d_in[21], (const float*)d_in[23], (const float*)d_in[25],
                        (const float*)d_in[27]};
  const float* gb[4] = {(const float*)d_in[22], (const float*)d_in[24], (const float*)d_in[26],
                        (const float*)d_in[28]};

  float* out = (float*)d_out;
  float* e_new = out;
  float* n_new = out + (size_t)NE * 128;
  float* g_new = n_new + (size_t)NNODES * 128;

  // workspace layout (edge weights contiguous: 36 x 16KB; node weights: 32 x 16KB)
  char* ws = (char*)d_ws;
  unsigned short* pe1 = (unsigned short*)ws;           // 512x256
  unsigned short* pe2 = pe1 + 512 * 256;               // 256x256
  unsigned short* pe3 = pe2 + 256 * 256;               // 256x256
  unsigned short* pe4 = pe3 + 256 * 256;               // 256x128
  unsigned short* pn1 = pe4 + 256 * 128;               // 384x256
  unsigned short* pn2 = pn1 + 384 * 256;               // 256x256
  unsigned short* pn3 = pn2 + 256 * 256;               // 256x256
  unsigned short* pn4 = pn3 + 256 * 256;               // 256x128
  float* agg = (float*)(ws + 1114112);                 // 20000x128 fp32
  float* esum = agg + (size_t)NNODES * 128;            // 128
  float* nsum = esum + 128;                            // 128

  hipMemsetAsync(agg, 0, (size_t)NNODES * 128 * 4 + 1024, stream);

  PackArgs pa;
  const float* srcs[8] = {ew[0], ew[1], ew[2], ew[3], nw[0], nw[1], nw[2], nw[3]};
  unsigned short* dsts[8] = {pe1, pe2, pe3, pe4, pn1, pn2, pn3, pn4};
  int Ks[8] = {512, 256, 256, 256, 384, 256, 256, 256};
  int Ns[8] = {256, 256, 256, 128, 256, 256, 256, 128};
  for (int i = 0; i < 8; ++i) {
    pa.src[i] = srcs[i];
    pa.dst[i] = dsts[i];
    pa.K[i] = Ks[i];
    pa.N[i] = Ns[i];
  }
  pack_weights<<<dim3(64, 8), 256, 0, stream>>>(pa);

  hipFuncSetAttribute((const void*)&fused_mlp<0>, hipFuncAttributeMaxDynamicSharedMemorySize,
                      SMEM_BYTES);
  hipFuncSetAttribute((const void*)&fused_mlp<1>, hipFuncAttributeMaxDynamicSharedMemorySize,
                      SMEM_BYTES);

  fused_mlp<0><<<NE / 64, 512, SMEM_BYTES, stream>>>(
      g, nodes, edges, senders, receivers, pe1, eb[0], eb[1], eb[2], eb[3], e_new, agg, esum);
  fused_mlp<1><<<(NNODES + 63) / 64, 512, SMEM_BYTES, stream>>>(
      g, nodes, agg, senders, receivers, pn1, nb[0], nb[1], nb[2], nb[3], n_new, nullptr, nsum);
  global_mlp<<<1, 384, 0, stream>>>(g, nsum, esum, gw[0], gb[0], gw[1], gb[1], gw[2], gb[2], gw[3],
                                    gb[3], g_new);
}

// Round 12
// 560.146 us; speedup vs baseline: 4.5864x; 4.5864x over previous
//
#include <hip/hip_runtime.h>
#include <stdint.h>

typedef __attribute__((ext_vector_type(8))) short bf16x8;
typedef __attribute__((ext_vector_type(4))) float f32x4;

#define NE 320000
#define NNODES 20000
// LDS: H 32768 | W0 16384 | W1 16384 | bias 3584 | colsum 512 = 69632 (2 blocks/CU)
#define SMEM_BYTES 69632

__device__ __forceinline__ unsigned short f2bf(float f) {
  union { float f; unsigned int u; } v; v.f = f;
  unsigned int u = v.u;
  u += 0x7fffu + ((u >> 16) & 1u);  // RNE
  return (unsigned short)(u >> 16);
}

__device__ __forceinline__ void gload_lds16(const void* g, void* l) {
  __builtin_amdgcn_global_load_lds((const __attribute__((address_space(1))) void*)g,
                                   (__attribute__((address_space(3))) void*)l, 16, 0, 0);
}

// ---- weight packing: W[K][N] fp32 -> A-fragment order (W^T frags) ----
// frag idx = s*NG + g (s = kstep of 32, g = 16-wide out group); 1KB per frag.
// element j of lane ln = W[s*32 + (ln>>4)*8 + j][g*16 + (ln&15)]
struct PackArgs {
  const float* src[8];
  unsigned short* dst[8];
  int K[8];
  int N[8];
};

__global__ void pack_weights(PackArgs a) {
  int m = blockIdx.y;
  int K = a.K[m], N = a.N[m];
  int NG = N >> 4;
  int total = (K >> 5) * NG * 64;
  int idx = blockIdx.x * 256 + threadIdx.x;
  if (idx >= total) return;
  int ln = idx & 63, f = idx >> 6;
  int g = f % NG, s = f / NG;
  const float* src = a.src[m];
  int krow = s * 32 + ((ln >> 4) & 3) * 8;
  int col = g * 16 + (ln & 15);
  bf16x8 p;
#pragma unroll
  for (int j = 0; j < 8; ++j) p[j] = (short)f2bf(src[(size_t)(krow + j) * N + col]);
  *(bf16x8*)(a.dst[m] + (size_t)idx * 8) = p;
}

// RNE bf16x8 from 8 fp32 (R1-proven numerics)
__device__ __forceinline__ bf16x8 cvt8(const f32x4& a, const f32x4& b) {
  bf16x8 r;
#pragma unroll
  for (int j = 0; j < 4; ++j) {
    r[j] = (short)f2bf(a[j]);
    r[4 + j] = (short)f2bf(b[j]);
  }
  return r;
}

// write relu(accT + bias) into H[m][n] bf16 (64 rows x 256 cols), stride 512B,
// XOR-swizzled; zero acc
__device__ __forceinline__ void store_H(char* Hb, const float* biasL, int boff,
                                        f32x4 (&acc)[2][4], int wm, int wn, int t, int cl) {
#pragma unroll
  for (int mg = 0; mg < 2; ++mg) {
    int m = wm * 32 + mg * 16 + cl;
    int sw = (m & 7) << 4;
    int mb = m * 512;
#pragma unroll
    for (int g = 0; g < 4; ++g) {
      int n = wn * 64 + g * 16 + t * 4;
      f32x4 bv = *(const f32x4*)(biasL + boff + n);
      f32x4 v = acc[mg][g] + bv;
#pragma unroll
      for (int j = 0; j < 4; ++j) v[j] = fmaxf(v[j], 0.0f);
      unsigned lo = (unsigned)f2bf(v[0]) | ((unsigned)f2bf(v[1]) << 16);
      unsigned hi = (unsigned)f2bf(v[2]) | ((unsigned)f2bf(v[3]) << 16);
      *(unsigned*)(Hb + ((mb + n * 2) ^ sw)) = lo;
      *(unsigned*)(Hb + ((mb + n * 2 + 4) ^ sw)) = hi;
      f32x4 z = {0.f, 0.f, 0.f, 0.f};
      acc[mg][g] = z;
    }
  }
}

// MODE 0: edge MLP (K1=512, X = [g|n_s|n_r|edges], agg atomics, e_sum)
// MODE 1: node MLP (K1=384, X = [g|nodes|agg], n_sum)
// pwAll = contiguous packed weights (w1|w2|w3|w4), 16KB chunks (kstep-of-32 each).
// Sync: __syncthreads() only. Overlap: {sync; issue stageW(c+1); compute(c)}.
// EPILOGUE RULE (R11 post-mortem): every agg atomic / outp store instruction must
// cover CONSECUTIVE dwords across lanes (full 64B lines). The R6-R11 column-strided
// pattern (each lane a different line) caused 16x the line-level RMW traffic
// (WRITE_SIZE 1.44GB vs 0.37GB) and the 5x slowdown.
template <int MODE>
__global__ __launch_bounds__(512, 4) void fused_mlp(
    const float* __restrict__ gvec, const float* __restrict__ nodes,
    const float* __restrict__ third, const int* __restrict__ senders,
    const int* __restrict__ receivers, const unsigned short* __restrict__ pwAll,
    const float* __restrict__ b1, const float* __restrict__ b2,
    const float* __restrict__ b3, const float* __restrict__ b4,
    float* __restrict__ outp, float* __restrict__ aggp, float* __restrict__ colsum) {
  constexpr int K1 = (MODE == 0) ? 512 : 384;
  constexpr int C1 = K1 / 32;          // L1 chunks of K=32 (16 / 12) — even
  constexpr int CT = C1 + 8 + 8 + 4;   // + L2 (8) + L3 (8) + L4 (4, K=64xN=128)
  constexpr int NROWS = (MODE == 0) ? NE : NNODES;

  extern __shared__ char smem[];
  char* Hb = smem;                        // 32768 : H [64][256] bf16 / [64][128] f32
  char* Wb0 = smem + 32768;               // 16384
  char* Wb1 = smem + 49152;               // 16384
  float* biasL = (float*)(smem + 65536);  // 896 floats
  float* csL = (float*)(smem + 69120);    // 128 floats

  const int tid = threadIdx.x;
  const int lane = tid & 63;
  const int wv = tid >> 6;            // 0..7
  const int wn = wv & 3;              // n-group quad (cols wn*64..+63)
  const int wm = wv >> 2;             // row half (rows wm*32..+31)
  const int t = lane >> 4, cl = lane & 15;
  const int row0 = blockIdx.x * 64;

  // ---- prologue: bias + colsum LDS ----
  for (int i = tid; i < 896; i += 512) {
    float bvv;
    if (i < 256) bvv = b1[i];
    else if (i < 512) bvv = b2[i - 256];
    else if (i < 768) bvv = b3[i - 512];
    else bvv = b4[i - 768];
    biasL[i] = bvv;
  }
  if (tid < 128) csL[tid] = 0.0f;

  // per-lane source row indices (2 m-groups of 16 rows)
  int ri[2], r1[2], r2[2];
#pragma unroll
  for (int mg = 0; mg < 2; ++mg) {
    int i = row0 + wm * 32 + mg * 16 + cl;
    if (MODE == 0) {
      ri[mg] = i;
      r1[mg] = senders[i];
      r2[mg] = receivers[i];
    } else {
      int iv = i < NROWS ? i : (NROWS - 1);
      ri[mg] = iv;
      r1[mg] = iv;
      r2[mg] = iv;
    }
  }

  // wave-uniform LDS staging: wave wv stages 1KB slices {2wv, 2wv+1} of the 16KB chunk
  auto stageW = [&](int gc) {
    if (gc >= CT) return;
    const char* p = (const char*)pwAll + (size_t)gc * 16384;
    char* d = (gc & 1) ? Wb1 : Wb0;
    const int s0 = wv << 1;  // wave-uniform slice index
    gload_lds16(p + (s0 << 10) + lane * 16, d + (s0 << 10));
    gload_lds16(p + ((s0 + 1) << 10) + lane * 16, d + ((s0 + 1) << 10));
  };

  // named ping/pong X buffers — all indices compile-time (rule #20 hedge)
  f32x4 xfA[2][2], xfB[2][2];
#define LOAD_X(BUF, c)                                                              \
  {                                                                                 \
    _Pragma("unroll") for (int mg = 0; mg < 2; ++mg) {                              \
      const int k0 = (c) * 32;                                                      \
      const int reg = k0 >> 7;                                                      \
      const int off = (k0 & 127) + t * 8;                                           \
      const float* sp;                                                              \
      if (MODE == 0) {                                                              \
        sp = (reg == 0)   ? gvec + off                                              \
             : (reg == 1) ? nodes + (size_t)r1[mg] * 128 + off                      \
             : (reg == 2) ? nodes + (size_t)r2[mg] * 128 + off                      \
                          : third + (size_t)ri[mg] * 128 + off;                     \
      } else {                                                                      \
        sp = (reg == 0)   ? gvec + off                                              \
             : (reg == 1) ? nodes + (size_t)r1[mg] * 128 + off                      \
                          : third + (size_t)r2[mg] * 128 + off;                     \
      }                                                                             \
      BUF[mg][0] = *(const f32x4*)sp;                                               \
      BUF[mg][1] = *(const f32x4*)(sp + 4);                                         \
    }                                                                               \
  }

  // one L1 step: sync; prefetch W(c+1); prefetch X(c+1)->XFN; MFMA on XFC + W(c)
#define L1_STEP(XFC, XFN, c)                                                        \
  {                                                                                 \
    __syncthreads();                                                                \
    stageW((c) + 1);                                                                \
    if ((c) + 1 < C1) LOAD_X(XFN, (c) + 1);                                         \
    bf16x8 xb[2];                                                                   \
    _Pragma("unroll") for (int mg = 0; mg < 2; ++mg)                                \
        xb[mg] = cvt8(XFC[mg][0], XFC[mg][1]);                                      \
    const char* wb = ((c) & 1) ? Wb1 : Wb0;                                         \
    _Pragma("unroll") for (int g = 0; g < 4; ++g) {                                 \
      bf16x8 af = *(const bf16x8*)(wb + ((wn * 4 + g) << 10) + lane * 16);          \
      _Pragma("unroll") for (int mg = 0; mg < 2; ++mg)                              \
          acc[mg][g] =                                                              \
              __builtin_amdgcn_mfma_f32_16x16x32_bf16(af, xb[mg], acc[mg][g], 0, 0, 0); \
    }                                                                               \
  }

  f32x4 acc[2][4];
  {
    f32x4 z = {0.f, 0.f, 0.f, 0.f};
#pragma unroll
    for (int mg = 0; mg < 2; ++mg)
#pragma unroll
      for (int g = 0; g < 4; ++g) acc[mg][g] = z;
  }

  stageW(0);
  LOAD_X(xfA, 0);

  // ---------------- layer 1 (explicit ping/pong pairs; C1 is even) ----------------
#pragma unroll
  for (int cc = 0; cc < C1 / 2; ++cc) {
    L1_STEP(xfA, xfB, 2 * cc);
    L1_STEP(xfB, xfA, 2 * cc + 1);
  }
  // store_H writes Hb; no wave reads Hb during L1 -> no extra sync needed here
  store_H(Hb, biasL, 0, acc, wm, wn, t, cl);

  // ---------------- layers 2,3 ----------------
#pragma unroll
  for (int L = 0; L < 2; ++L) {
    const int base = C1 + L * 8;
#pragma unroll
    for (int c = 0; c < 8; ++c) {
      __syncthreads();               // store_H visible (c=0); W(base+c) drained
      stageW(base + c + 1);
      const char* wb = ((base + c) & 1) ? Wb1 : Wb0;
      bf16x8 bfm[2];
#pragma unroll
      for (int mg = 0; mg < 2; ++mg) {
        int m = wm * 32 + mg * 16 + cl;
        int off = (m * 512 + c * 64 + t * 16) ^ ((m & 7) << 4);
        bfm[mg] = *(const bf16x8*)(Hb + off);
      }
#pragma unroll
      for (int g = 0; g < 4; ++g) {
        bf16x8 af = *(const bf16x8*)(wb + ((wn * 4 + g) << 10) + lane * 16);
#pragma unroll
        for (int mg = 0; mg < 2; ++mg)
          acc[mg][g] = __builtin_amdgcn_mfma_f32_16x16x32_bf16(af, bfm[mg], acc[mg][g], 0, 0, 0);
      }
    }
    __syncthreads();                 // all Hb reads of this layer retired
    store_H(Hb, biasL, 256 + L * 256, acc, wm, wn, t, cl);
  }

  // ---------------- layer 4 (N=128, chunks = K=64 x 128) ----------------
  {
    const int base = C1 + 16;
#pragma unroll
    for (int c = 0; c < 4; ++c) {
      __syncthreads();
      stageW(base + c + 1);          // guarded >= CT inside
      const char* wb = ((base + c) & 1) ? Wb1 : Wb0;
#pragma unroll
      for (int s2 = 0; s2 < 2; ++s2) {
        bf16x8 bfm[2];
#pragma unroll
        for (int mg = 0; mg < 2; ++mg) {
          int m = wm * 32 + mg * 16 + cl;
          int off = (m * 512 + c * 128 + s2 * 64 + t * 16) ^ ((m & 7) << 4);
          bfm[mg] = *(const bf16x8*)(Hb + off);
        }
#pragma unroll
        for (int g = 0; g < 2; ++g) {
          bf16x8 af = *(const bf16x8*)(wb + ((s2 * 8 + wn * 2 + g) << 10) + lane * 16);
#pragma unroll
          for (int mg = 0; mg < 2; ++mg)
            acc[mg][g] = __builtin_amdgcn_mfma_f32_16x16x32_bf16(af, bfm[mg], acc[mg][g], 0, 0, 0);
        }
      }
    }
  }
  __syncthreads();                   // all Hb (H3) reads retired before overwrite

  // ---------------- epilogue ----------------
  // write acc + b4 as f32 into Hb [64][128], stride 512B, swizzled
#pragma unroll
  for (int mg = 0; mg < 2; ++mg) {
    int m = wm * 32 + mg * 16 + cl;
    int sw = (m & 7) << 4;
    int mb = m * 512;
#pragma unroll
    for (int g = 0; g < 2; ++g) {
      int n = wn * 32 + g * 16 + t * 4;
      f32x4 bv = *(const f32x4*)(biasL + 768 + n);
      f32x4 v = acc[mg][g] + bv;
      float2 p0 = {v[0], v[1]}, p1 = {v[2], v[3]};
      *(float2*)(Hb + ((mb + n * 4) ^ sw)) = p0;
      *(float2*)(Hb + ((mb + n * 4 + 8) ^ sw)) = p1;
    }
  }
  __syncthreads();

  // COALESCED writeback: wave wv owns rows wv*8..+7; per row, lane covers col
  // h*64+lane (h=0,1) -> every store/atomic instruction = 64 consecutive dwords.
  {
    float cs[2] = {0.f, 0.f};
#pragma unroll
    for (int rr = 0; rr < 8; ++rr) {
      int r = wv * 8 + rr;                 // wave-uniform
      int e = row0 + r;                    // wave-uniform
      bool valid = (MODE == 0) ? true : (e < NROWS);
      int rcv = (MODE == 0 && valid) ? receivers[e] : 0;  // scalar load
      float vh[2];
#pragma unroll
      for (int h = 0; h < 2; ++h) {
        int off = (r * 512 + (h * 64 + lane) * 4) ^ ((r & 7) << 4);
        float v = *(const float*)(Hb + off);
        vh[h] = valid ? v : 0.0f;
      }
      if (valid) {
        float* op = outp + (size_t)e * 128 + lane;
        op[0] = vh[0];
        op[64] = vh[1];
        if (MODE == 0) {
          float* ap = aggp + (size_t)rcv * 128 + lane;
          atomicAdd(ap, vh[0]);
          atomicAdd(ap + 64, vh[1]);
        }
      }
      cs[0] += vh[0];
      cs[1] += vh[1];
    }
    atomicAdd(&csL[lane], cs[0]);
    atomicAdd(&csL[64 + lane], cs[1]);
  }
  __syncthreads();
  if (tid < 128) atomicAdd(colsum + tid, csL[tid]);
#undef LOAD_X
#undef L1_STEP
}

// tiny fp32 global MLP: x = [g | n_sum | e_sum]
__global__ void global_mlp(const float* __restrict__ g, const float* __restrict__ nsum,
                           const float* __restrict__ esum, const float* __restrict__ w1,
                           const float* __restrict__ bb1, const float* __restrict__ w2,
                           const float* __restrict__ bb2, const float* __restrict__ w3,
                           const float* __restrict__ bb3, const float* __restrict__ w4,
                           const float* __restrict__ bb4, float* __restrict__ outg) {
  __shared__ float x[384], h1[256], h2[256], h3[256];
  int tq = threadIdx.x;
  if (tq < 128) x[tq] = g[tq];
  else if (tq < 256) x[tq] = nsum[tq - 128];
  else x[tq] = esum[tq - 256];
  __syncthreads();
  if (tq < 256) {
    float a = bb1[tq];
    for (int k = 0; k < 384; ++k) a = fmaf(x[k], w1[k * 256 + tq], a);
    h1[tq] = fmaxf(a, 0.f);
  }
  __syncthreads();
  if (tq < 256) {
    float a = bb2[tq];
    for (int k = 0; k < 256; ++k) a = fmaf(h1[k], w2[k * 256 + tq], a);
    h2[tq] = fmaxf(a, 0.f);
  }
  __syncthreads();
  if (tq < 256) {
    float a = bb3[tq];
    for (int k = 0; k < 256; ++k) a = fmaf(h2[k], w3[k * 256 + tq], a);
    h3[tq] = fmaxf(a, 0.f);
  }
  __syncthreads();
  if (tq < 128) {
    float a = bb4[tq];
    for (int k = 0; k < 256; ++k) a = fmaf(h3[k], w4[k * 128 + tq], a);
    outg[tq] = a;
  }
}

extern "C" void kernel_launch(void* const* d_in, const int* in_sizes, int n_in, void* d_out,
                              int out_size, void* d_ws, size_t ws_size, hipStream_t stream) {
  const float* g = (const float*)d_in[0];
  const float* nodes = (const float*)d_in[1];
  const float* edges = (const float*)d_in[2];
  const int* senders = (const int*)d_in[3];
  const int* receivers = (const int*)d_in[4];
  const float* ew[4] = {(const float*)d_in[5], (const float*)d_in[7], (const float*)d_in[9],
                        (const float*)d_in[11]};
  const float* eb[4] = {(const float*)d_in[6], (const float*)d_in[8], (const float*)d_in[10],
                        (const float*)d_in[12]};
  const float* nw[4] = {(const float*)d_in[13], (const float*)d_in[15], (const float*)d_in[17],
                        (const float*)d_in[19]};
  const float* nb[4] = {(const float*)d_in[14], (const float*)d_in[16], (const float*)d_in[18],
                        (const float*)d_in[20]};
  const float* gw[4] = {(const float*)d_in[21], (const float*)d_in[23], (const float*)d_in[25],
                        (const float*)d_in[27]};
  const float* gb[4] = {(const float*)d_in[22], (const float*)d_in[24], (const float*)d_in[26],
                        (const float*)d_in[28]};

  float* out = (float*)d_out;
  float* e_new = out;
  float* n_new = out + (size_t)NE * 128;
  float* g_new = n_new + (size_t)NNODES * 128;

  // workspace layout (edge weights contiguous: 36 x 16KB; node weights: 32 x 16KB)
  char* ws = (char*)d_ws;
  unsigned short* pe1 = (unsigned short*)ws;           // 512x256
  unsigned short* pe2 = pe1 + 512 * 256;               // 256x256
  unsigned short* pe3 = pe2 + 256 * 256;               // 256x256
  unsigned short* pe4 = pe3 + 256 * 256;               // 256x128
  unsigned short* pn1 = pe4 + 256 * 128;               // 384x256
  unsigned short* pn2 = pn1 + 384 * 256;               // 256x256
  unsigned short* pn3 = pn2 + 256 * 256;               // 256x256
  unsigned short* pn4 = pn3 + 256 * 256;               // 256x128
  float* agg = (float*)(ws + 1114112);                 // 20000x128 fp32
  float* esum = agg + (size_t)NNODES * 128;            // 128
  float* nsum = esum + 128;                            // 128

  hipMemsetAsync(agg, 0, (size_t)NNODES * 128 * 4 + 1024, stream);

  PackArgs pa;
  const float* srcs[8] = {ew[0], ew[1], ew[2], ew[3], nw[0], nw[1], nw[2], nw[3]};
  unsigned short* dsts[8] = {pe1, pe2, pe3, pe4, pn1, pn2, pn3, pn4};
  int Ks[8] = {512, 256, 256, 256, 384, 256, 256, 256};
  int Ns[8] = {256, 256, 256, 128, 256, 256, 256, 128};
  for (int i = 0; i < 8; ++i) {
    pa.src[i] = srcs[i];
    pa.dst[i] = dsts[i];
    pa.K[i] = Ks[i];
    pa.N[i] = Ns[i];
  }
  pack_weights<<<dim3(64, 8), 256, 0, stream>>>(pa);

  hipFuncSetAttribute((const void*)&fused_mlp<0>, hipFuncAttributeMaxDynamicSharedMemorySize,
                      SMEM_BYTES);
  hipFuncSetAttribute((const void*)&fused_mlp<1>, hipFuncAttributeMaxDynamicSharedMemorySize,
                      SMEM_BYTES);

  fused_mlp<0><<<NE / 64, 512, SMEM_BYTES, stream>>>(
      g, nodes, edges, senders, receivers, pe1, eb[0], eb[1], eb[2], eb[3], e_new, agg, esum);
  fused_mlp<1><<<(NNODES + 63) / 64, 512, SMEM_BYTES, stream>>>(
      g, nodes, agg, senders, receivers, pn1, nb[0], nb[1], nb[2], nb[3], n_new, nullptr, nsum);
  global_mlp<<<1, 384, 0, stream>>>(g, nsum, esum, gw[0], gb[0], gw[1], gb[1], gw[2], gb[2], gw[3],
                                    gb[3], g_new);
}